// Round 1
// 589.503 us; speedup vs baseline: 1.0177x; 1.0177x over previous
//
#include <hip/hip_runtime.h>
#include <hip/hip_bf16.h>

typedef __hip_bfloat16 bf16;
typedef __attribute__((ext_vector_type(4))) float  floatx4;
typedef __attribute__((ext_vector_type(8))) short  short8;
typedef __attribute__((ext_vector_type(8))) __bf16 bf16x8;

constexpr int Bc = 4, Lc = 1024, Sc = 1024, DIMc = 1024, NHc = 16, DHc = 64;

// ---- MFMA dispatcher: works whether the builtin takes short8 or bf16x8 ----
template <typename V>
__device__ auto mfma_bf16_sel(V a, V b, floatx4 c, int)
    -> decltype(__builtin_amdgcn_mfma_f32_16x16x32_bf16(a, b, c, 0, 0, 0)) {
  return __builtin_amdgcn_mfma_f32_16x16x32_bf16(a, b, c, 0, 0, 0);
}
template <typename V>
__device__ floatx4 mfma_bf16_sel(V a, V b, floatx4 c, long) {
  bf16x8 a2 = __builtin_bit_cast(bf16x8, a);
  bf16x8 b2 = __builtin_bit_cast(bf16x8, b);
  return __builtin_amdgcn_mfma_f32_16x16x32_bf16(a2, b2, c, 0, 0, 0);
}
__device__ inline floatx4 mfma_bf16(short8 a, short8 b, floatx4 c) {
  return mfma_bf16_sel(a, b, c, 0);
}

union U8 { uint4 u; bf16 h[8]; };

__device__ inline U8 load8(const float* p) {
    float4 f0 = ((const float4*)p)[0];
    float4 f1 = ((const float4*)p)[1];
    U8 t;
    t.h[0] = __float2bfloat16(f0.x); t.h[1] = __float2bfloat16(f0.y);
    t.h[2] = __float2bfloat16(f0.z); t.h[3] = __float2bfloat16(f0.w);
    t.h[4] = __float2bfloat16(f1.x); t.h[5] = __float2bfloat16(f1.y);
    t.h[6] = __float2bfloat16(f1.z); t.h[7] = __float2bfloat16(f1.w);
    return t;
}

// ---------------------------------------------------------------------------
// Prep: blocks [0,1024): transpose+cast the 4 weights into Wt[n][k] bf16
//       via 64x64 LDS tiles (256 blocks per weight).
//       blocks [1024,1280): bit-pack the int mask (16 rows/block) into
//       mbits[row][w] (64 bits each) and precompute rowany[row] (causal-aware).
// ---------------------------------------------------------------------------
__global__ __launch_bounds__(256)
void prep_kernel(const float* __restrict__ Wq, const float* __restrict__ Wk,
                 const float* __restrict__ Wv, const float* __restrict__ Wp,
                 const int* __restrict__ mask, const int* __restrict__ is_causal_p,
                 bf16* __restrict__ wqt, bf16* __restrict__ wkt,
                 bf16* __restrict__ wvt, bf16* __restrict__ wpt,
                 unsigned long long* __restrict__ mbits,
                 int* __restrict__ rowany_g)
{
    __shared__ float tile[64][68];
    const int tid = threadIdx.x;
    int blk = blockIdx.x;

    if (blk < 1024) {
        const int w  = blk >> 8, t2 = blk & 255;
        const float* W  = (w == 0) ? Wq : (w == 1) ? Wk : (w == 2) ? Wv : Wp;
        bf16*        Wt = (w == 0) ? wqt : (w == 1) ? wkt : (w == 2) ? wvt : wpt;
        const int tk = (t2 >> 4) << 6;   // k-tile base
        const int tn = (t2 & 15) << 6;   // n-tile base
        #pragma unroll
        for (int i = 0; i < 4; ++i) {
            const int r = (tid >> 4) + i * 16;   // 0..63 (k within tile)
            const int c = (tid & 15) << 2;       // 0..60 (n within tile)
            *(float4*)(&tile[r][c]) =
                *(const float4*)(W + (size_t)(tk + r) * DIMc + tn + c);
        }
        __syncthreads();
        #pragma unroll
        for (int j = 0; j < 2; ++j) {
            const int nn = tid >> 2;                  // 0..63
            const int kc = (tid & 3) + j * 4;         // 0..7
            U8 o;
            #pragma unroll
            for (int u = 0; u < 8; ++u)
                o.h[u] = __float2bfloat16(tile[kc * 8 + u][nn]);
            *(uint4*)(Wt + (size_t)(tn + nn) * DIMc + tk + kc * 8) = o.u;
        }
    } else {
        const int mb  = blk - 1024;          // 0..255
        const int rIb = tid >> 4;            // 0..15
        const int w   = tid & 15;            // 64-bit word within row
        const int row = mb * 16 + rIb;       // 0..4095  (b*1024 + l)
        const int l   = row & (Lc - 1);
        const bool causal = (is_causal_p[0] != 0);

        const int4* mr4 = (const int4*)(mask + (size_t)row * Sc + w * 64);
        unsigned long long bits = 0ull;
        #pragma unroll
        for (int i = 0; i < 16; ++i) {
            int4 m4 = mr4[i];
            unsigned long long nib =
                (unsigned long long)((m4.x != 0) | ((m4.y != 0) << 1) |
                                     ((m4.z != 0) << 2) | ((m4.w != 0) << 3));
            bits |= nib << (4 * i);
        }
        mbits[(size_t)row * 16 + w] = bits;

        const int limit = causal ? l : (Sc - 1);
        const int base  = w * 64;
        unsigned long long am;
        if (limit >= base + 63)  am = bits;
        else if (limit < base)   am = 0ull;
        else                     am = bits & ((2ull << (limit - base)) - 1ull);
        unsigned long long red = am;
        #pragma unroll
        for (int d2 = 1; d2 < 16; d2 <<= 1) red |= __shfl_xor(red, d2);
        if (w == 0) rowany_g[row] = (red != 0ull) ? 1 : 0;
    }
}

// ---------------------------------------------------------------------------
// Fused QKV GEMM (B^T form): blockIdx.z selects {q,k,v}. A is fp32, cast to
// bf16 during reg-staging (eliminates the separate cast pass + round-trip).
// C[m][n] = sum_k A[m][k]*Bt[n][k] + bias[n].  128x128 tile, BK=64, 4 waves
// 2x2, each wave 64x64 = 4x4 MFMA tiles.  LDS stride 72 (bank-even).
// z<2 -> out[((b*NH+h)*L + l)*DH + d] bf16 ; z==2 -> out[((b*NH+h)*DH+d)*S+l]
// ---------------------------------------------------------------------------
constexpr int GPAD = 72;

__global__ __launch_bounds__(256)
void gemm_qkv_kernel(const float* __restrict__ q, const float* __restrict__ k,
                     const float* __restrict__ v,
                     const bf16* __restrict__ wqt, const bf16* __restrict__ wkt,
                     const bf16* __restrict__ wvt,
                     const float* __restrict__ bq, const float* __restrict__ bk,
                     const float* __restrict__ bv,
                     bf16* __restrict__ qh, bf16* __restrict__ kh,
                     bf16* __restrict__ vt)
{
    __shared__ bf16 As[128 * GPAD];
    __shared__ bf16 Bs[128 * GPAD];

    const int z = blockIdx.z;
    const float* A    = (z == 0) ? q   : (z == 1) ? k   : v;
    const bf16*  Bt   = (z == 0) ? wqt : (z == 1) ? wkt : wvt;
    const float* bias = (z == 0) ? bq  : (z == 1) ? bk  : bv;
    bf16*        out  = (z == 0) ? qh  : (z == 1) ? kh  : vt;

    const int tid  = threadIdx.x;
    const int wave = tid >> 6;
    const int lane = tid & 63;
    const int n = lane & 15, g = lane >> 4;
    const int m0 = blockIdx.x * 128;
    const int n0 = blockIdx.y * 128;
    const int wq_m = (wave & 1) * 64, wq_n = (wave >> 1) * 64;

    floatx4 acc[4][4];
    #pragma unroll
    for (int a = 0; a < 4; ++a)
        #pragma unroll
        for (int b2 = 0; b2 < 4; ++b2)
            acc[a][b2] = (floatx4){0.f, 0.f, 0.f, 0.f};

    const int srow   = tid >> 3;          // 0..31
    const int schunk = (tid & 7) * 8;     // 0..56

    for (int k0 = 0; k0 < DIMc; k0 += 64) {
        #pragma unroll
        for (int i = 0; i < 4; ++i) {
            const int r = srow + i * 32;
            U8 a8 = load8(A + (size_t)(m0 + r) * DIMc + k0 + schunk);
            *(uint4*)(&As[r * GPAD + schunk]) = a8.u;
            *(uint4*)(&Bs[r * GPAD + schunk]) =
                *(const uint4*)(Bt + (size_t)(n0 + r) * DIMc + k0 + schunk);
        }
        __syncthreads();
        #pragma unroll
        for (int ks = 0; ks < 2; ++ks) {
            short8 af[4], bf_[4];
            #pragma unroll
            for (int t = 0; t < 4; ++t) {
                af[t]  = *(const short8*)(&As[(wq_m + t * 16 + n) * GPAD + ks * 32 + g * 8]);
                bf_[t] = *(const short8*)(&Bs[(wq_n + t * 16 + n) * GPAD + ks * 32 + g * 8]);
            }
            #pragma unroll
            for (int tm = 0; tm < 4; ++tm)
                #pragma unroll
                for (int tn = 0; tn < 4; ++tn)
                    acc[tm][tn] = mfma_bf16(af[tm], bf_[tn], acc[tm][tn]);
        }
        __syncthreads();
    }

    // epilogue: C/D layout col = lane&15 (=n), row = g*4 + r
    #pragma unroll
    for (int tn = 0; tn < 4; ++tn) {
        const int col = n0 + wq_n + tn * 16 + n;
        const float bval = bias[col];
        #pragma unroll
        for (int tm = 0; tm < 4; ++tm) {
            #pragma unroll
            for (int r = 0; r < 4; ++r) {
                const int row = m0 + wq_m + tm * 16 + g * 4 + r;
                const float vv = acc[tm][tn][r] + bval;
                const int bb = row >> 10, ll = row & (Lc - 1);
                const int hh = col >> 6,  dd = col & 63;
                size_t idx;
                if (z < 2) idx = (((size_t)(bb * NHc + hh) * Lc + ll) * DHc) + dd;
                else       idx = (((size_t)(bb * NHc + hh) * DHc + dd) * Sc) + ll;
                out[idx] = __float2bfloat16(vv);
            }
        }
    }
}

// ---------------------------------------------------------------------------
// Output-projection GEMM: A bf16 (attention output), fp32 out, row-major.
// ---------------------------------------------------------------------------
__global__ __launch_bounds__(256)
void gemm_out_kernel(const bf16* __restrict__ A, const bf16* __restrict__ Bt,
                     const float* __restrict__ bias, float* __restrict__ out)
{
    __shared__ bf16 As[128 * GPAD];
    __shared__ bf16 Bs[128 * GPAD];

    const int tid  = threadIdx.x;
    const int wave = tid >> 6;
    const int lane = tid & 63;
    const int n = lane & 15, g = lane >> 4;
    const int m0 = blockIdx.x * 128;
    const int n0 = blockIdx.y * 128;
    const int wq_m = (wave & 1) * 64, wq_n = (wave >> 1) * 64;

    floatx4 acc[4][4];
    #pragma unroll
    for (int a = 0; a < 4; ++a)
        #pragma unroll
        for (int b2 = 0; b2 < 4; ++b2)
            acc[a][b2] = (floatx4){0.f, 0.f, 0.f, 0.f};

    const int srow   = tid >> 3;
    const int schunk = (tid & 7) * 8;

    for (int k0 = 0; k0 < DIMc; k0 += 64) {
        #pragma unroll
        for (int i = 0; i < 4; ++i) {
            const int r = srow + i * 32;
            *(uint4*)(&As[r * GPAD + schunk]) =
                *(const uint4*)(A + (size_t)(m0 + r) * DIMc + k0 + schunk);
            *(uint4*)(&Bs[r * GPAD + schunk]) =
                *(const uint4*)(Bt + (size_t)(n0 + r) * DIMc + k0 + schunk);
        }
        __syncthreads();
        #pragma unroll
        for (int ks = 0; ks < 2; ++ks) {
            short8 af[4], bf_[4];
            #pragma unroll
            for (int t = 0; t < 4; ++t) {
                af[t]  = *(const short8*)(&As[(wq_m + t * 16 + n) * GPAD + ks * 32 + g * 8]);
                bf_[t] = *(const short8*)(&Bs[(wq_n + t * 16 + n) * GPAD + ks * 32 + g * 8]);
            }
            #pragma unroll
            for (int tm = 0; tm < 4; ++tm)
                #pragma unroll
                for (int tn = 0; tn < 4; ++tn)
                    acc[tm][tn] = mfma_bf16(af[tm], bf_[tn], acc[tm][tn]);
        }
        __syncthreads();
    }

    #pragma unroll
    for (int tn = 0; tn < 4; ++tn) {
        const int col = n0 + wq_n + tn * 16 + n;
        const float bval = bias[col];
        #pragma unroll
        for (int tm = 0; tm < 4; ++tm) {
            #pragma unroll
            for (int r = 0; r < 4; ++r) {
                const int row = m0 + wq_m + tm * 16 + g * 4 + r;
                out[(size_t)row * DIMc + col] = acc[tm][tn][r] + bval;
            }
        }
    }
}

// ---------------------------------------------------------------------------
// Flash MFMA attention.  Score-column remap: QK^T tile t reads K LDS row
// (4n+t), so lane n's 4 score columns are s = s0+4n..4n+3 (contiguous).
// Bias -> one float4/row, mask -> nibble from pre-packed bits, P -> one
// 8B LDS write.  rowany precomputed in prep.
// ---------------------------------------------------------------------------
constexpr int PADk = 72;

__global__ __launch_bounds__(256)
void flash_attn_kernel(const bf16* __restrict__ qh, const bf16* __restrict__ kh,
                       const bf16* __restrict__ vt,
                       const unsigned long long* __restrict__ mbits,
                       const int* __restrict__ rowany_g,
                       const float* __restrict__ pos_bias,
                       const int* __restrict__ is_causal_p, bf16* __restrict__ o)
{
    __shared__ bf16 Ks[64 * PADk];
    __shared__ bf16 Vs[64 * PADk];
    __shared__ bf16 Pw[4][16 * PADk];
    __shared__ int rowany[64];
    __shared__ int hasfix_s;

    const int tid  = threadIdx.x;
    const int lane = tid & 63;
    const int wave = tid >> 6;
    const int n = lane & 15;
    const int g = lane >> 4;

    const int qt = blockIdx.x & 15;
    const int bh = blockIdx.x >> 4;
    const int h  = bh & (NHc - 1);
    const int b  = bh >> 4;
    const int l0 = qt * 64;
    const bool causal = (is_causal_p[0] != 0);

    if (tid == 0) hasfix_s = 0;
    __syncthreads();
    if (tid < 64) {
        const int ra = rowany_g[(b << 10) + l0 + tid];
        rowany[tid] = ra;
        if (ra == 0) atomicOr(&hasfix_s, 1);
    }
    __syncthreads();
    const bool hasfix = (hasfix_s != 0);

    const int qrow_frag = l0 + wave * 16 + n;
    const bf16* qp = qh + ((size_t)bh * Lc + qrow_frag) * DHc;
    const short8 qf0 = *(const short8*)(qp + g * 8);
    const short8 qf1 = *(const short8*)(qp + 32 + g * 8);

    floatx4 oacc[4];
    #pragma unroll
    for (int t = 0; t < 4; ++t) oacc[t] = (floatx4){0.f, 0.f, 0.f, 0.f};
    float m_run[4], l_run[4];
    #pragma unroll
    for (int r = 0; r < 4; ++r) { m_run[r] = -3.0e38f; l_run[r] = 0.f; }

    int nchunk = Sc / 64;
    if (causal && !hasfix) nchunk = qt + 1;

    for (int c = 0; c < nchunk; ++c) {
        const int s0 = c * 64;
        __syncthreads();
        #pragma unroll
        for (int it = 0; it < 2; ++it) {
            const int e  = tid * 8 + it * 2048;
            const int r0 = e >> 6, c0 = e & 63;
            *(uint4*)(Ks + r0 * PADk + c0) =
                *(const uint4*)(kh + ((size_t)bh * Sc + s0 + r0) * DHc + c0);
            *(uint4*)(Vs + r0 * PADk + c0) =
                *(const uint4*)(vt + ((size_t)bh * DHc + r0) * Sc + s0 + c0);
        }
        __syncthreads();

        // per-row bias (float4, coalesced) + packed mask nibble
        float bvv[4][4]; int nib[4];
        #pragma unroll
        for (int r = 0; r < 4; ++r) {
            const int l = l0 + wave * 16 + g * 4 + r;
            const float4 b4 =
                *(const float4*)(pos_bias + ((size_t)bh * Lc + l) * Sc + s0 + 4 * n);
            bvv[r][0] = b4.x; bvv[r][1] = b4.y; bvv[r][2] = b4.z; bvv[r][3] = b4.w;
            const unsigned long long wbits = mbits[((size_t)(b << 10) + l) * 16 + c];
            nib[r] = (int)((wbits >> (4 * n)) & 15ull);
        }

        floatx4 scv[4];
        #pragma unroll
        for (int t = 0; t < 4; ++t) scv[t] = (floatx4){0.f, 0.f, 0.f, 0.f};
        #pragma unroll
        for (int t = 0; t < 4; ++t) {
            const bf16* kp = Ks + (4 * n + t) * PADk + g * 8;
            short8 kb0 = *(const short8*)(kp);
            short8 kb1 = *(const short8*)(kp + 32);
            scv[t] = mfma_bf16(qf0, kb0, scv[t]);
            scv[t] = mfma_bf16(qf1, kb1, scv[t]);
        }

        #pragma unroll
        for (int r = 0; r < 4; ++r) {
            const int row = wave * 16 + g * 4 + r;
            const int l = l0 + row;
            const int limit = causal ? l : (Sc - 1);
            const bool fix = (rowany[row] == 0);
            float vals[4];
            #pragma unroll
            for (int t = 0; t < 4; ++t) {
                const int s = s0 + 4 * n + t;
                const bool ok = fix || (s <= limit && ((nib[r] >> t) & 1));
                vals[t] = ok ? scv[t][r] * 0.125f + bvv[r][t] : -3.0e38f;
            }
            float cm = fmaxf(fmaxf(vals[0], vals[1]), fmaxf(vals[2], vals[3]));
            cm = fmaxf(cm, __shfl_xor(cm, 1));
            cm = fmaxf(cm, __shfl_xor(cm, 2));
            cm = fmaxf(cm, __shfl_xor(cm, 4));
            cm = fmaxf(cm, __shfl_xor(cm, 8));
            const float mnew = fmaxf(m_run[r], cm);
            const float alpha = __expf(m_run[r] - mnew);
            float csum = 0.f;
            union PK { uint2 u; bf16 hb[4]; } pk;
            #pragma unroll
            for (int t = 0; t < 4; ++t) {
                const float p = (vals[t] < -1.0e37f) ? 0.f : __expf(vals[t] - mnew);
                csum += p;
                pk.hb[t] = __float2bfloat16(p);
            }
            *(uint2*)(&Pw[wave][(row & 15) * PADk + 4 * n]) = pk.u;
            csum += __shfl_xor(csum, 1);
            csum += __shfl_xor(csum, 2);
            csum += __shfl_xor(csum, 4);
            csum += __shfl_xor(csum, 8);
            l_run[r] = l_run[r] * alpha + csum;
            m_run[r] = mnew;
            #pragma unroll
            for (int t = 0; t < 4; ++t) oacc[t][r] *= alpha;
        }
        // no barrier needed: Pw is wave-private (ds dependency handles order)

        #pragma unroll
        for (int sc2 = 0; sc2 < 2; ++sc2) {
            short8 pa = *(const short8*)(Pw[wave] + n * PADk + sc2 * 32 + g * 8);
            #pragma unroll
            for (int t = 0; t < 4; ++t) {
                short8 vb = *(const short8*)(Vs + (16 * t + n) * PADk + sc2 * 32 + g * 8);
                oacc[t] = mfma_bf16(pa, vb, oacc[t]);
            }
        }
    }

    #pragma unroll
    for (int r = 0; r < 4; ++r) {
        const int l = l0 + wave * 16 + g * 4 + r;
        const float inv = 1.f / l_run[r];
        #pragma unroll
        for (int t = 0; t < 4; ++t) {
            const int d = 16 * t + n;
            o[((size_t)(b * Lc + l)) * DIMc + h * DHc + d] =
                __float2bfloat16(oacc[t][r] * inv);
        }
    }
}

// ---------------------------------------------------------------------------
extern "C" void kernel_launch(void* const* d_in, const int* in_sizes, int n_in,
                              void* d_out, int out_size, void* d_ws, size_t ws_size,
                              hipStream_t stream)
{
    (void)in_sizes; (void)n_in; (void)out_size; (void)ws_size;

    const float* q        = (const float*)d_in[0];
    const float* k        = (const float*)d_in[1];
    const float* v        = (const float*)d_in[2];
    const int*   mask     = (const int*)d_in[3];
    const float* pos_bias = (const float*)d_in[4];
    const float* Wq = (const float*)d_in[5];
    const float* bq = (const float*)d_in[6];
    const float* Wk = (const float*)d_in[7];
    const float* bk = (const float*)d_in[8];
    const float* Wv = (const float*)d_in[9];
    const float* bv = (const float*)d_in[10];
    const float* Wp = (const float*)d_in[11];
    const float* bp = (const float*)d_in[12];
    const int*   is_causal = (const int*)d_in[13];

    const size_t per = (size_t)Bc * NHc * Lc * DHc;   // 4M elems
    const size_t wsz = (size_t)DIMc * DIMc;           // 1M elems
    bf16* qh  = (bf16*)d_ws;
    bf16* kh  = qh + per;
    bf16* vt  = kh + per;
    bf16* oh  = vt + per;
    bf16* wqt = oh + per;
    bf16* wkt = wqt + wsz;
    bf16* wvt = wkt + wsz;
    bf16* wpt = wvt + wsz;
    unsigned long long* mbits = (unsigned long long*)(wpt + wsz);
    int* rowany_g = (int*)(mbits + (size_t)Bc * Lc * 16);
    float* outp = (float*)d_out;

    dim3 bb(256);

    prep_kernel<<<1280, bb, 0, stream>>>(Wq, Wk, Wv, Wp, mask, is_causal,
                                         wqt, wkt, wvt, wpt, mbits, rowany_g);

    dim3 gq(32, 8, 3);   // 4096/128 x 1024/128 x {q,k,v}
    gemm_qkv_kernel<<<gq, bb, 0, stream>>>(q, k, v, wqt, wkt, wvt,
                                           bq, bk, bv, qh, kh, vt);

    flash_attn_kernel<<<(Bc * NHc) * (Lc / 64), bb, 0, stream>>>(
        qh, kh, vt, mbits, rowany_g, pos_bias, is_causal, oh);

    dim3 gg(32, 8);
    gemm_out_kernel<<<gg, bb, 0, stream>>>(oh, wpt, bp, outp);
}